// Round 4
// baseline (344.138 us; speedup 1.0000x reference)
//
#include <hip/hip_runtime.h>
#include <math.h>

typedef float f4 __attribute__((ext_vector_type(4)));
typedef float f32x4 __attribute__((ext_vector_type(4)));
typedef _Float16 h4 __attribute__((ext_vector_type(4)));
typedef _Float16 h8 __attribute__((ext_vector_type(8)));

#define BH 32
#define NN 4096
#define DD 64
#define FF 256
#define EE 64
#define SPLITS 16   // kside splits (512 blocks -> 2 blocks/CU)
#define ROWS_K 256  // rows per kside block
#define QB 16       // qside splits (512 blocks -> 2 blocks/CU)
#define ROWS_Q 256  // rows per qside block
#define ST 72       // Pt stride (f16), padded (R0-proven)
#define STF 264     // qside kvt stride (256 + 8 pad)

#define MFMA(a, b, c) __builtin_amdgcn_mfma_f32_16x16x32_f16((a), (b), (c), 0, 0, 0)
#define MFMA16(a, b, c) __builtin_amdgcn_mfma_f32_16x16x16f16((a), (b), (c), 0, 0, 0)

__device__ inline h8 cvt2(f4 x0, f4 x1) {
  h8 r;
  r[0] = (_Float16)x0.x; r[1] = (_Float16)x0.y;
  r[2] = (_Float16)x0.z; r[3] = (_Float16)x0.w;
  r[4] = (_Float16)x1.x; r[5] = (_Float16)x1.y;
  r[6] = (_Float16)x1.z; r[7] = (_Float16)x1.w;
  return r;
}

// ---------------------------------------------------------------------------
// kside: grid 32*16, 256 thr (4 waves). 2 blocks/CU (LDS 77KB) -> two
// independent barrier domains interleave stalls. Per-wave stream identical
// to R0: 64-row tiles, wave owns 16-row strip, full-f proj, in-wave softmax.
// kpt: unpadded [256][64] with granule-XOR swizzle (per-lane-const masks) ->
// conflict-free GEMM reads. kv partials stored f16.
// ---------------------------------------------------------------------------
__global__ __launch_bounds__(256, 2) void fa_kside(
    const float* __restrict__ kin, const float* __restrict__ vin,
    const float* __restrict__ P, _Float16* __restrict__ kv_part,
    float* __restrict__ ksum_part) {
  __shared__ _Float16 Pt[FF * ST];    // 36.9 KB  P^T[f][d], padded
  __shared__ _Float16 kpt[FF * 64];   // 32 KB    kp^T[f][krow], swizzled
  __shared__ _Float16 vt[EE * 72];    // 9.2 KB   v^T[e][krow], padded
  // ksum reduce area aliases vt (vt dead after last GEMM)
  float* ks_lds = (float*)vt;         // 4 KB needed <= 9.2 KB

  const int t = threadIdx.x;
  const int w = t >> 6, lane = t & 63;
  const int g = lane >> 4, fl = lane & 15;
  const int bh = blockIdx.x >> 4, split = blockIdx.x & 15;
  const int bhs = blockIdx.x;
  const int k0 = g * 8;
  const int swz = (fl & 7) << 3;  // kpt granule-XOR mask (per-lane const)

  {  // stage P^T (f16)
    const f4* Pg4 = (const f4*)P;
#pragma unroll
    for (int i = 0; i < 16; ++i) {
      int idx = t + i * 256;
      f4 pv = Pg4[idx];
      int d = idx >> 6, f0 = (idx & 63) * 4;
      Pt[(f0 + 0) * ST + d] = (_Float16)pv.x;
      Pt[(f0 + 1) * ST + d] = (_Float16)pv.y;
      Pt[(f0 + 2) * ST + d] = (_Float16)pv.z;
      Pt[(f0 + 3) * ST + d] = (_Float16)pv.w;
    }
  }

  f32x4 kvacc[4][4];
#pragma unroll
  for (int mi = 0; mi < 4; ++mi)
#pragma unroll
    for (int nt = 0; nt < 4; ++nt) kvacc[mi][nt] = (f32x4){0.f, 0.f, 0.f, 0.f};
  float ksum_acc[16];
#pragma unroll
  for (int T = 0; T < 16; ++T) ksum_acc[T] = 0.f;

  const size_t base = (size_t)bh * NN * DD + (size_t)split * ROWS_K * DD;
  __syncthreads();  // Pt ready

  for (int tile = 0; tile < 4; ++tile) {
    if (tile) __syncthreads();  // WAR: previous GEMM reads done
    const int r0g = tile * 64 + w * 16;

    // A fragments of k directly from global (row = r0g+fl)
    const float* krow = kin + base + (size_t)(r0g + fl) * DD;
    h8 a0 = cvt2(*(const f4*)&krow[k0], *(const f4*)&krow[k0 + 4]);
    h8 a1 = cvt2(*(const f4*)&krow[32 + k0], *(const f4*)&krow[32 + k0 + 4]);

    // v^T staging: lane owns e=lane, wave's 16 rows
    {
      const float* vb = vin + base + (size_t)r0g * DD + lane;
      h8 tv0, tv1;
#pragma unroll
      for (int j = 0; j < 8; ++j) tv0[j] = (_Float16)vb[j * DD];
#pragma unroll
      for (int j = 0; j < 8; ++j) tv1[j] = (_Float16)vb[(8 + j) * DD];
      *(h8*)&vt[lane * 72 + w * 16] = tv0;
      *(h8*)&vt[lane * 72 + w * 16 + 8] = tv1;
    }

    // projection: full 256 features for this wave's strip
    f32x4 lac[16];
#pragma unroll
    for (int T = 0; T < 16; ++T) {
      int ncol = T * 16 + fl;
      h8 b0 = *(const h8*)&Pt[ncol * ST + k0];
      h8 b1 = *(const h8*)&Pt[ncol * ST + 32 + k0];
      f32x4 c = {0.f, 0.f, 0.f, 0.f};
      c = MFMA(a0, b0, c);
      c = MFMA(a1, b1, c);
      lac[T] = c;
    }

    // in-wave rowmax (row = strip g*4+rg; features spread over fl lanes)
    float mrow[4];
#pragma unroll
    for (int rg = 0; rg < 4; ++rg) {
      float m = lac[0][rg];
#pragma unroll
      for (int T = 1; T < 16; ++T) m = fmaxf(m, lac[T][rg]);
#pragma unroll
      for (int off = 1; off <= 8; off <<= 1)
        m = fmaxf(m, __shfl_xor(m, off, 64));
      mrow[rg] = m;
    }

    // exp + kp^T write (swizzled) + ksum accumulate
    const int kcol = (w * 16 + g * 4) ^ swz;  // per-lane const column
#pragma unroll
    for (int T = 0; T < 16; ++T) {
      int ncol = T * 16 + fl;
      h4 kp;
#pragma unroll
      for (int rg = 0; rg < 4; ++rg) {
        float ev = __expf(lac[T][rg] - mrow[rg]) * 0.0625f;
        _Float16 hv = (_Float16)ev;
        ksum_acc[T] += (float)hv;
        kp[rg] = hv;
      }
      *(h4*)&kpt[ncol * 64 + kcol] = kp;
    }
    __syncthreads();  // kpt + vt ready

    // kv GEMM: wave owns f-tiles {4w..4w+3} x 4 e-tiles, k = 64 rows
    const int rc0 = (0 * 32 + k0) ^ swz;  // swizzled read cols (const)
    const int rc1 = (1 * 32 + k0) ^ swz;
#pragma unroll
    for (int kst = 0; kst < 2; ++kst) {
      const int rcs = kst ? rc1 : rc0;
      h8 vbf[4];
#pragma unroll
      for (int nt = 0; nt < 4; ++nt)
        vbf[nt] = *(const h8*)&vt[(nt * 16 + fl) * 72 + kst * 32 + k0];
#pragma unroll
      for (int mi = 0; mi < 4; ++mi) {
        h8 ka = *(const h8*)&kpt[((4 * w + mi) * 16 + fl) * 64 + rcs];
#pragma unroll
        for (int nt = 0; nt < 4; ++nt)
          kvacc[mi][nt] = MFMA(ka, vbf[nt], kvacc[mi][nt]);
      }
    }
  }

  // write kv partial (f16)
  _Float16* kvp = kv_part + (size_t)bhs * (FF * EE);
#pragma unroll
  for (int mi = 0; mi < 4; ++mi)
#pragma unroll
    for (int nt = 0; nt < 4; ++nt)
#pragma unroll
      for (int rg = 0; rg < 4; ++rg) {
        int f = (4 * w + mi) * 16 + g * 4 + rg;
        int e = nt * 16 + fl;
        kvp[f * EE + e] = (_Float16)kvacc[mi][nt][rg];
      }

  // ksum partial: reduce over g in-wave, then cross-wave via LDS (aliases vt)
  __syncthreads();  // all GEMM reads of vt done before alias reuse
#pragma unroll
  for (int T = 0; T < 16; ++T) {
    float s = ksum_acc[T];
    s += __shfl_xor(s, 16, 64);
    s += __shfl_xor(s, 32, 64);
    if (lane < 16) ks_lds[w * FF + T * 16 + lane] = s;
  }
  __syncthreads();
  {
    float s = 0.f;
#pragma unroll
    for (int wi = 0; wi < 4; ++wi) s += ks_lds[wi * FF + t];
    ksum_part[(size_t)bhs * FF + t] = s;
  }
}

// ---------------------------------------------------------------------------
// reduce: 544 blocks x 256 thr. Blocks 0..511: one (bh, 16-f-slice) each,
// sum 16 f16 partials + LDS transpose -> kvt f16 [e][f]. Blocks 512..543: ksum.
// ---------------------------------------------------------------------------
__global__ __launch_bounds__(256) void fa_reduce(
    const _Float16* __restrict__ kv_part, const float* __restrict__ ksum_part,
    _Float16* __restrict__ kvt_g, float* __restrict__ ksum_g) {
  __shared__ _Float16 tl[EE * 18];
  const int b = blockIdx.x, t = threadIdx.x;
  if (b < 512) {
    const int bh = b >> 4, c = b & 15;
#pragma unroll
    for (int i = 0; i < 4; ++i) {
      int idx = i * 256 + t;
      int fr = idx >> 6, e = idx & 63;
      float s = 0.f;
#pragma unroll
      for (int sp = 0; sp < SPLITS; ++sp)
        s += (float)kv_part[(size_t)(bh * SPLITS + sp) * (FF * EE) +
                            (c * 16 + fr) * EE + e];
      tl[e * 18 + fr] = (_Float16)s;
    }
    __syncthreads();
    unsigned int* og = (unsigned int*)kvt_g + (size_t)bh * 8192;
#pragma unroll
    for (int i = 0; i < 2; ++i) {
      int idx = i * 256 + t;
      int e = idx >> 3, fp = (idx & 7) * 2;
      og[e * 128 + c * 8 + (idx & 7)] = *(unsigned int*)&tl[e * 18 + fp];
    }
  } else {
    const int bh = b - 512;
    float s = 0.f;
#pragma unroll
    for (int sp = 0; sp < SPLITS; ++sp)
      s += ksum_part[(size_t)(bh * SPLITS + sp) * FF + t];
    ksum_g[bh * FF + t] = s + 1e-6f;
  }
}

// ---------------------------------------------------------------------------
// qside: grid 32*16, 512 thr (8 waves), 2 blocks/CU (LDS 71.7KB), 4 w/SIMD.
// SWAPPED projection: MFMA(P_frag, q_frag) -> lane holds qp[f][qrow=fl];
// rowmax/den via 2 shuffles; packed h4 per T' feeds 16x16x16 out GEMM B-frag
// directly (no qpt LDS at all, zero inner barriers). Out GEMM swapped too:
// C[e][qrow], den scaling uniform per lane, f4 output stores.
// ---------------------------------------------------------------------------
__global__ __launch_bounds__(512, 4) void fa_qside(
    const float* __restrict__ qin, const float* __restrict__ P,
    const _Float16* __restrict__ kvt_g, const float* __restrict__ ksum_g,
    float* __restrict__ out) {
  __shared__ _Float16 Pt[FF * ST];     // 36.9 KB, padded
  __shared__ _Float16 kvt[EE * STF];   // 33.8 KB kv^T[e][f], padded
  __shared__ float ks_lds[FF];         // 1 KB ksum (f32)

  const int t = threadIdx.x;
  const int w = t >> 6, lane = t & 63;
  const int g = lane >> 4, fl = lane & 15;
  const int bh = blockIdx.x >> 4, qb = blockIdx.x & 15;
  const int k0 = g * 8;

  {  // stage P^T
    const f4* Pg4 = (const f4*)P;
#pragma unroll
    for (int i = 0; i < 8; ++i) {
      int idx = t + i * 512;
      f4 pv = Pg4[idx];
      int d = idx >> 6, f0 = (idx & 63) * 4;
      Pt[(f0 + 0) * ST + d] = (_Float16)pv.x;
      Pt[(f0 + 1) * ST + d] = (_Float16)pv.y;
      Pt[(f0 + 2) * ST + d] = (_Float16)pv.z;
      Pt[(f0 + 3) * ST + d] = (_Float16)pv.w;
    }
  }
  {  // stage kv^T
    const h8* src = (const h8*)(kvt_g + (size_t)bh * FF * EE);
#pragma unroll
    for (int i = 0; i < 4; ++i) {
      int idx = t + i * 512;
      int e = idx >> 5, f0 = (idx & 31) * 8;
      *(h8*)&kvt[e * STF + f0] = src[idx];
    }
  }
  if (t < FF) ks_lds[t] = ksum_g[bh * FF + t];
  __syncthreads();  // the only barrier

  const size_t base = (size_t)bh * NN * DD + (size_t)qb * ROWS_Q * DD;
  float* ob = out + (size_t)bh * NN * EE + (size_t)qb * ROWS_Q * EE;

  for (int st = 0; st < 2; ++st) {
    const int r0g = st * 128 + w * 16;
    const float* qrow = qin + base + (size_t)(r0g + fl) * DD;
    h8 a0 = cvt2(*(const f4*)&qrow[k0], *(const f4*)&qrow[k0 + 4]);
    h8 a1 = cvt2(*(const f4*)&qrow[32 + k0], *(const f4*)&qrow[32 + k0 + 4]);

    // swapped projection: lac[T'][rg] = qp[f=16T'+4g+rg][qrow=fl]
    f32x4 lac[16];
#pragma unroll
    for (int T = 0; T < 16; ++T) {
      int ncol = T * 16 + fl;
      h8 b0 = *(const h8*)&Pt[ncol * ST + k0];
      h8 b1 = *(const h8*)&Pt[ncol * ST + 32 + k0];
      f32x4 c = {0.f, 0.f, 0.f, 0.f};
      c = MFMA(b0, a0, c);  // A=P^T (f rows), B=q^T (qrow cols)
      c = MFMA(b1, a1, c);
      lac[T] = c;
    }

    // rowmax for qrow=fl: in-lane tree (64 vals) + cross-g butterfly
    float m = lac[0][0];
#pragma unroll
    for (int T = 0; T < 16; ++T)
#pragma unroll
      for (int rg = 0; rg < 4; ++rg) m = fmaxf(m, lac[T][rg]);
    m = fmaxf(m, __shfl_xor(m, 16, 64));
    m = fmaxf(m, __shfl_xor(m, 32, 64));

    // exp + pack h4 per T' + denominator partial (broadcast ksum reads)
    h4 qp4[16];
    float den = 0.f;
#pragma unroll
    for (int T = 0; T < 16; ++T) {
      f4 ksf = *(const f4*)&ks_lds[T * 16 + g * 4];
#pragma unroll
      for (int rg = 0; rg < 4; ++rg) {
        float ev = __expf(lac[T][rg] - m) * 0.0625f;
        _Float16 hv = (_Float16)ev;
        den += (float)hv * ksf[rg];
        qp4[T][rg] = hv;
      }
    }
    den += __shfl_xor(den, 16, 64);
    den += __shfl_xor(den, 32, 64);
    const float inv = 1.0f / den;

    // out GEMM (16x16x16, swapped): C[e][qrow=fl]; A=kvt rows e, B=qp4 direct
    f32x4 oacc[4];
#pragma unroll
    for (int nt = 0; nt < 4; ++nt) oacc[nt] = (f32x4){0.f, 0.f, 0.f, 0.f};
#pragma unroll
    for (int kst = 0; kst < 16; ++kst) {
#pragma unroll
      for (int nt = 0; nt < 4; ++nt) {
        h4 av = *(const h4*)&kvt[(nt * 16 + fl) * STF + kst * 16 + g * 4];
        oacc[nt] = MFMA16(av, qp4[kst], oacc[nt]);
      }
    }

    // store: lane holds out[qrow=fl][e = nt*16 + g*4 + rg], f4 per e-tile
    float* obt = ob + (size_t)(r0g + fl) * EE;
#pragma unroll
    for (int nt = 0; nt < 4; ++nt) {
      f4 o;
#pragma unroll
      for (int rg = 0; rg < 4; ++rg) o[rg] = oacc[nt][rg] * inv;
      *(f4*)&obt[nt * 16 + g * 4] = o;
    }
  }
}

extern "C" void kernel_launch(void* const* d_in, const int* in_sizes, int n_in,
                              void* d_out, int out_size, void* d_ws,
                              size_t ws_size, hipStream_t stream) {
  (void)in_sizes;
  (void)n_in;
  (void)out_size;
  (void)ws_size;
  const float* q = (const float*)d_in[0];
  const float* k = (const float*)d_in[1];
  const float* v = (const float*)d_in[2];
  const float* P = (const float*)d_in[3];
  float* out = (float*)d_out;

  _Float16* kv_part = (_Float16*)d_ws;                    // 512*16384 f16 = 16.8 MB
  float* ksum_part = (float*)(kv_part + 512 * 16384);     // 512*256 f32 = 0.5 MB
  _Float16* kvt_g = (_Float16*)(ksum_part + 512 * 256);   // 32*16384 f16 = 1 MB
  float* ksum_g = (float*)(kvt_g + 32 * 16384);           // 32*256 f32

  hipLaunchKernelGGL(fa_kside, dim3(BH * SPLITS), dim3(256), 0, stream, k, v, P,
                     kv_part, ksum_part);
  hipLaunchKernelGGL(fa_reduce, dim3(544), dim3(256), 0, stream, kv_part,
                     ksum_part, kvt_g, ksum_g);
  hipLaunchKernelGGL(fa_qside, dim3(BH * QB), dim3(512), 0, stream, q, P, kvt_g,
                     ksum_g, out);
}

// Round 5
// 177.272 us; speedup vs baseline: 1.9413x; 1.9413x over previous
//
#include <hip/hip_runtime.h>
#include <math.h>

typedef float f4 __attribute__((ext_vector_type(4)));
typedef float f32x4 __attribute__((ext_vector_type(4)));
typedef _Float16 h4 __attribute__((ext_vector_type(4)));
typedef _Float16 h8 __attribute__((ext_vector_type(8)));

#define BH 32
#define NN 4096
#define DD 64
#define FF 256
#define EE 64
#define SPLITS 16   // kside splits (512 blocks -> 2 blocks/CU)
#define ROWS_K 256  // rows per kside block
#define QB 8        // qside splits (256 blocks -> 1 block/CU, R0-proven)
#define ROWS_Q 512  // rows per qside block
#define ST 72       // Pt stride (f16), padded (R0-proven)
#define STF 264     // qside qpt/kvt stride (256 + 8 pad)

#define MFMA(a, b, c) __builtin_amdgcn_mfma_f32_16x16x32_f16((a), (b), (c), 0, 0, 0)

__device__ inline h8 cvt2(f4 x0, f4 x1) {
  h8 r;
  r[0] = (_Float16)x0.x; r[1] = (_Float16)x0.y;
  r[2] = (_Float16)x0.z; r[3] = (_Float16)x0.w;
  r[4] = (_Float16)x1.x; r[5] = (_Float16)x1.y;
  r[6] = (_Float16)x1.z; r[7] = (_Float16)x1.w;
  return r;
}

// ---------------------------------------------------------------------------
// kside: grid 32*16, 256 thr (4 waves). LDS 77KB -> 2 blocks/CU: two
// independent barrier domains interleave each other's latency/barrier stalls.
// Per-wave stream identical to R0: wave owns a 16-row strip, full-f proj,
// in-wave softmax. 64-row tiles. kpt: unpadded [256][64] with granule-XOR
// swizzle (masks are per-lane consts). kv partials stored f16.
// NOTE: no forced occupancy in launch_bounds (R4 lesson: forcing it caps
// VGPR and spills); VGPR cap stays 256, LDS is the occupancy knob.
// ---------------------------------------------------------------------------
__global__ __launch_bounds__(256, 2) void fa_kside(
    const float* __restrict__ kin, const float* __restrict__ vin,
    const float* __restrict__ P, _Float16* __restrict__ kv_part,
    float* __restrict__ ksum_part) {
  __shared__ _Float16 Pt[FF * ST];    // 36.9 KB  P^T[f][d], padded
  __shared__ _Float16 kpt[FF * 64];   // 32 KB    kp^T[f][krow], swizzled
  __shared__ _Float16 vt[EE * 72];    // 9.2 KB   v^T[e][krow], padded
  // ksum reduce area aliases vt (vt dead after last GEMM)
  float* ks_lds = (float*)vt;         // 4 KB needed <= 9.2 KB

  const int t = threadIdx.x;
  const int w = t >> 6, lane = t & 63;
  const int g = lane >> 4, fl = lane & 15;
  const int bh = blockIdx.x >> 4, split = blockIdx.x & 15;
  const int bhs = blockIdx.x;
  const int k0 = g * 8;
  const int swz = (fl & 7) << 3;  // kpt granule-XOR mask (per-lane const)

  {  // stage P^T (f16)
    const f4* Pg4 = (const f4*)P;
#pragma unroll
    for (int i = 0; i < 16; ++i) {
      int idx = t + i * 256;
      f4 pv = Pg4[idx];
      int d = idx >> 6, f0 = (idx & 63) * 4;
      Pt[(f0 + 0) * ST + d] = (_Float16)pv.x;
      Pt[(f0 + 1) * ST + d] = (_Float16)pv.y;
      Pt[(f0 + 2) * ST + d] = (_Float16)pv.z;
      Pt[(f0 + 3) * ST + d] = (_Float16)pv.w;
    }
  }

  f32x4 kvacc[4][4];
#pragma unroll
  for (int mi = 0; mi < 4; ++mi)
#pragma unroll
    for (int nt = 0; nt < 4; ++nt) kvacc[mi][nt] = (f32x4){0.f, 0.f, 0.f, 0.f};
  float ksum_acc[16];
#pragma unroll
  for (int T = 0; T < 16; ++T) ksum_acc[T] = 0.f;

  const size_t base = (size_t)bh * NN * DD + (size_t)split * ROWS_K * DD;
  __syncthreads();  // Pt ready

  for (int tile = 0; tile < 4; ++tile) {
    if (tile) __syncthreads();  // WAR: previous GEMM reads done
    const int r0g = tile * 64 + w * 16;

    // A fragments of k directly from global (row = r0g+fl)
    const float* krow = kin + base + (size_t)(r0g + fl) * DD;
    h8 a0 = cvt2(*(const f4*)&krow[k0], *(const f4*)&krow[k0 + 4]);
    h8 a1 = cvt2(*(const f4*)&krow[32 + k0], *(const f4*)&krow[32 + k0 + 4]);

    // v^T staging: lane owns e=lane, wave's 16 rows
    {
      const float* vb = vin + base + (size_t)r0g * DD + lane;
      h8 tv0, tv1;
#pragma unroll
      for (int j = 0; j < 8; ++j) tv0[j] = (_Float16)vb[j * DD];
#pragma unroll
      for (int j = 0; j < 8; ++j) tv1[j] = (_Float16)vb[(8 + j) * DD];
      *(h8*)&vt[lane * 72 + w * 16] = tv0;
      *(h8*)&vt[lane * 72 + w * 16 + 8] = tv1;
    }

    // projection: full 256 features for this wave's strip
    f32x4 lac[16];
#pragma unroll
    for (int T = 0; T < 16; ++T) {
      int ncol = T * 16 + fl;
      h8 b0 = *(const h8*)&Pt[ncol * ST + k0];
      h8 b1 = *(const h8*)&Pt[ncol * ST + 32 + k0];
      f32x4 c = {0.f, 0.f, 0.f, 0.f};
      c = MFMA(a0, b0, c);
      c = MFMA(a1, b1, c);
      lac[T] = c;
    }

    // in-wave rowmax
    float mrow[4];
#pragma unroll
    for (int rg = 0; rg < 4; ++rg) {
      float m = lac[0][rg];
#pragma unroll
      for (int T = 1; T < 16; ++T) m = fmaxf(m, lac[T][rg]);
#pragma unroll
      for (int off = 1; off <= 8; off <<= 1)
        m = fmaxf(m, __shfl_xor(m, off, 64));
      mrow[rg] = m;
    }

    // exp + kp^T write (swizzled) + ksum accumulate
    const int kcol = (w * 16 + g * 4) ^ swz;  // per-lane const column
#pragma unroll
    for (int T = 0; T < 16; ++T) {
      int ncol = T * 16 + fl;
      h4 kp;
#pragma unroll
      for (int rg = 0; rg < 4; ++rg) {
        float ev = __expf(lac[T][rg] - mrow[rg]) * 0.0625f;
        _Float16 hv = (_Float16)ev;
        ksum_acc[T] += (float)hv;
        kp[rg] = hv;
      }
      *(h4*)&kpt[ncol * 64 + kcol] = kp;
    }
    __syncthreads();  // kpt + vt ready

    // kv GEMM: wave owns f-tiles {4w..4w+3} x 4 e-tiles, k = 64 rows
    const int rc0 = (0 * 32 + k0) ^ swz;  // swizzled read cols (const)
    const int rc1 = (1 * 32 + k0) ^ swz;
#pragma unroll
    for (int kst = 0; kst < 2; ++kst) {
      const int rcs = kst ? rc1 : rc0;
      h8 vbf[4];
#pragma unroll
      for (int nt = 0; nt < 4; ++nt)
        vbf[nt] = *(const h8*)&vt[(nt * 16 + fl) * 72 + kst * 32 + k0];
#pragma unroll
      for (int mi = 0; mi < 4; ++mi) {
        h8 ka = *(const h8*)&kpt[((4 * w + mi) * 16 + fl) * 64 + rcs];
#pragma unroll
        for (int nt = 0; nt < 4; ++nt)
          kvacc[mi][nt] = MFMA(ka, vbf[nt], kvacc[mi][nt]);
      }
    }
  }

  // write kv partial (f16)
  _Float16* kvp = kv_part + (size_t)bhs * (FF * EE);
#pragma unroll
  for (int mi = 0; mi < 4; ++mi)
#pragma unroll
    for (int nt = 0; nt < 4; ++nt)
#pragma unroll
      for (int rg = 0; rg < 4; ++rg) {
        int f = (4 * w + mi) * 16 + g * 4 + rg;
        int e = nt * 16 + fl;
        kvp[f * EE + e] = (_Float16)kvacc[mi][nt][rg];
      }

  // ksum partial: reduce over g in-wave, then cross-wave via LDS (aliases vt)
  __syncthreads();  // all GEMM reads of vt done before alias reuse
#pragma unroll
  for (int T = 0; T < 16; ++T) {
    float s = ksum_acc[T];
    s += __shfl_xor(s, 16, 64);
    s += __shfl_xor(s, 32, 64);
    if (lane < 16) ks_lds[w * FF + T * 16 + lane] = s;
  }
  __syncthreads();
  {
    float s = 0.f;
#pragma unroll
    for (int wi = 0; wi < 4; ++wi) s += ks_lds[wi * FF + t];
    ksum_part[(size_t)bhs * FF + t] = s;
  }
}

// ---------------------------------------------------------------------------
// reduce: 544 blocks x 256 thr. Blocks 0..511: one (bh, 16-f-slice) each,
// sum 16 f16 partials + LDS transpose -> kvt f16 [e][f]. Blocks 512..543: ksum.
// ---------------------------------------------------------------------------
__global__ __launch_bounds__(256) void fa_reduce(
    const _Float16* __restrict__ kv_part, const float* __restrict__ ksum_part,
    _Float16* __restrict__ kvt_g, float* __restrict__ ksum_g) {
  __shared__ _Float16 tl[EE * 18];
  const int b = blockIdx.x, t = threadIdx.x;
  if (b < 512) {
    const int bh = b >> 4, c = b & 15;
#pragma unroll
    for (int i = 0; i < 4; ++i) {
      int idx = i * 256 + t;
      int fr = idx >> 6, e = idx & 63;
      float s = 0.f;
#pragma unroll
      for (int sp = 0; sp < SPLITS; ++sp)
        s += (float)kv_part[(size_t)(bh * SPLITS + sp) * (FF * EE) +
                            (c * 16 + fr) * EE + e];
      tl[e * 18 + fr] = (_Float16)s;
    }
    __syncthreads();
    unsigned int* og = (unsigned int*)kvt_g + (size_t)bh * 8192;
#pragma unroll
    for (int i = 0; i < 2; ++i) {
      int idx = i * 256 + t;
      int e = idx >> 3, fp = (idx & 7) * 2;
      og[e * 128 + c * 8 + (idx & 7)] = *(unsigned int*)&tl[e * 18 + fp];
    }
  } else {
    const int bh = b - 512;
    float s = 0.f;
#pragma unroll
    for (int sp = 0; sp < SPLITS; ++sp)
      s += ksum_part[(size_t)(bh * SPLITS + sp) * FF + t];
    ksum_g[bh * FF + t] = s + 1e-6f;
  }
}

// ---------------------------------------------------------------------------
// qside: grid 32*8, 512 thr — R0-EXACT (proven ~40us, VGPR 104). ZERO
// inner-loop barriers: wave owns 16-row strips; q A-frags direct from
// global; rowmax/exp/denom in-wave; C->A transpose through wave-private
// LDS region; kvt/Pt read-only shared.
// ---------------------------------------------------------------------------
__global__ __launch_bounds__(512, 2) void fa_qside(
    const float* __restrict__ qin, const float* __restrict__ P,
    const _Float16* __restrict__ kvt_g, const float* __restrict__ ksum_g,
    float* __restrict__ out) {
  __shared__ _Float16 Pt[FF * ST];        // 36.9 KB
  __shared__ _Float16 kvt[EE * STF];      // 33.8 KB kv^T[e][f]
  __shared__ _Float16 qpt[8 * 16 * STF];  // 67.6 KB wave-private qp[row][f]

  const int t = threadIdx.x;
  const int w = t >> 6, lane = t & 63;
  const int g = lane >> 4, fl = lane & 15;
  const int bh = blockIdx.x >> 3, qb = blockIdx.x & 7;
  const int k0 = g * 8;

  {  // stage P^T
    const f4* Pg4 = (const f4*)P;
#pragma unroll
    for (int i = 0; i < 8; ++i) {
      int idx = t + i * 512;
      f4 pv = Pg4[idx];
      int d = idx >> 6, f0 = (idx & 63) * 4;
      Pt[(f0 + 0) * ST + d] = (_Float16)pv.x;
      Pt[(f0 + 1) * ST + d] = (_Float16)pv.y;
      Pt[(f0 + 2) * ST + d] = (_Float16)pv.z;
      Pt[(f0 + 3) * ST + d] = (_Float16)pv.w;
    }
  }
  {  // stage kv^T
    const h8* src = (const h8*)(kvt_g + (size_t)bh * FF * EE);
#pragma unroll
    for (int i = 0; i < 4; ++i) {
      int idx = t + i * 512;
      int e = idx >> 5, f0 = (idx & 31) * 8;
      *(h8*)&kvt[e * STF + f0] = src[idx];
    }
  }
  float ksr[16];
#pragma unroll
  for (int T = 0; T < 16; ++T) ksr[T] = ksum_g[bh * FF + T * 16 + fl];
  __syncthreads();  // the only barrier

  _Float16* myqpt = qpt + w * 16 * STF;
  const size_t base = (size_t)bh * NN * DD + (size_t)qb * ROWS_Q * DD;
  float* ob = out + (size_t)bh * NN * EE + (size_t)qb * ROWS_Q * EE;

  for (int st = 0; st < 4; ++st) {
    const int r0g = st * 128 + w * 16;
    const float* qrow = qin + base + (size_t)(r0g + fl) * DD;
    h8 a0 = cvt2(*(const f4*)&qrow[k0], *(const f4*)&qrow[k0 + 4]);
    h8 a1 = cvt2(*(const f4*)&qrow[32 + k0], *(const f4*)&qrow[32 + k0 + 4]);

    f32x4 lac[16];
#pragma unroll
    for (int T = 0; T < 16; ++T) {
      int ncol = T * 16 + fl;
      h8 b0 = *(const h8*)&Pt[ncol * ST + k0];
      h8 b1 = *(const h8*)&Pt[ncol * ST + 32 + k0];
      f32x4 c = {0.f, 0.f, 0.f, 0.f};
      c = MFMA(a0, b0, c);
      c = MFMA(a1, b1, c);
      lac[T] = c;
    }

    float mrow[4];
#pragma unroll
    for (int rg = 0; rg < 4; ++rg) {
      float m = lac[0][rg];
#pragma unroll
      for (int T = 1; T < 16; ++T) m = fmaxf(m, lac[T][rg]);
#pragma unroll
      for (int off = 1; off <= 8; off <<= 1)
        m = fmaxf(m, __shfl_xor(m, off, 64));
      mrow[rg] = m;
    }

    float den[4] = {0.f, 0.f, 0.f, 0.f};
#pragma unroll
    for (int T = 0; T < 16; ++T) {
      int ncol = T * 16 + fl;
#pragma unroll
      for (int rg = 0; rg < 4; ++rg) {
        float ev = __expf(lac[T][rg] - mrow[rg]) * 0.0625f;
        _Float16 hv = (_Float16)ev;
        den[rg] += (float)hv * ksr[T];
        myqpt[(g * 4 + rg) * STF + ncol] = hv;
      }
    }
#pragma unroll
    for (int rg = 0; rg < 4; ++rg) {
#pragma unroll
      for (int off = 1; off <= 8; off <<= 1)
        den[rg] += __shfl_xor(den[rg], off, 64);
    }

    // out GEMM: A = myqpt (wave-private, in-order DS pipeline), B = kvt
    f32x4 oacc[4];
#pragma unroll
    for (int nt = 0; nt < 4; ++nt) oacc[nt] = (f32x4){0.f, 0.f, 0.f, 0.f};
#pragma unroll
    for (int kst = 0; kst < 8; ++kst) {
      h8 aq = *(const h8*)&myqpt[fl * STF + kst * 32 + k0];
#pragma unroll
      for (int nt = 0; nt < 4; ++nt) {
        h8 bq = *(const h8*)&kvt[(nt * 16 + fl) * STF + kst * 32 + k0];
        oacc[nt] = MFMA(aq, bq, oacc[nt]);
      }
    }

    float* obt = ob + (size_t)r0g * EE;
#pragma unroll
    for (int rg = 0; rg < 4; ++rg) {
      float inv = 1.0f / den[rg];
#pragma unroll
      for (int nt = 0; nt < 4; ++nt) {
        int e = nt * 16 + fl;
        obt[(g * 4 + rg) * EE + e] = oacc[nt][rg] * inv;
      }
    }
  }
}

extern "C" void kernel_launch(void* const* d_in, const int* in_sizes, int n_in,
                              void* d_out, int out_size, void* d_ws,
                              size_t ws_size, hipStream_t stream) {
  (void)in_sizes;
  (void)n_in;
  (void)out_size;
  (void)ws_size;
  const float* q = (const float*)d_in[0];
  const float* k = (const float*)d_in[1];
  const float* v = (const float*)d_in[2];
  const float* P = (const float*)d_in[3];
  float* out = (float*)d_out;

  _Float16* kv_part = (_Float16*)d_ws;                    // 512*16384 f16 = 16.8 MB
  float* ksum_part = (float*)(kv_part + 512 * 16384);     // 512*256 f32 = 0.5 MB
  _Float16* kvt_g = (_Float16*)(ksum_part + 512 * 256);   // 32*16384 f16 = 1 MB
  float* ksum_g = (float*)(kvt_g + 32 * 16384);           // 32*256 f32

  hipLaunchKernelGGL(fa_kside, dim3(BH * SPLITS), dim3(256), 0, stream, k, v, P,
                     kv_part, ksum_part);
  hipLaunchKernelGGL(fa_reduce, dim3(544), dim3(256), 0, stream, kv_part,
                     ksum_part, kvt_g, ksum_g);
  hipLaunchKernelGGL(fa_qside, dim3(BH * QB), dim3(512), 0, stream, q, P, kvt_g,
                     ksum_g, out);
}